// Round 1
// baseline (6376.878 us; speedup 1.0000x reference)
//
#include <hip/hip_runtime.h>

// Sinkhorn-log barycentric mapping, N=M=8192, D=128, reg=0.05, 50 iters.
// d_out layout: [ mapped: N*D f32 | pi: N*M f32 ].
// Mr = -C/reg is materialized in the pi region (overwritten by pi at the end).
// Scratch (u, v, xx, yy, partials) lives inside the mapped region, which is
// fully overwritten by the final k_mapped kernel. d_ws is NOT used.

#define NN 8192
#define MMX 8192
#define DD 128
#define NITER 50
#define LOGAB (-9.0109133472792881f)   /* log(1/8192) = -13*ln2 */
#define NEG20 (-20.0f)                 /* -1/reg */

static __device__ __forceinline__ void lse_acc(float& m, float& s, float x) {
    float mn = fmaxf(m, x);
    s = s * __expf(m - mn) + __expf(x - mn);
    m = mn;
}
static __device__ __forceinline__ void lse_merge(float& m, float& s, float m2, float s2) {
    float mn = fmaxf(m, m2);
    s = s * __expf(m - mn) + s2 * __expf(m2 - mn);
    m = mn;
}
static __device__ __forceinline__ void lse_acc4(float4& m, float4& s, float4 x) {
    lse_acc(m.x, s.x, x.x);
    lse_acc(m.y, s.y, x.y);
    lse_acc(m.z, s.z, x.z);
    lse_acc(m.w, s.w, x.w);
}
static __device__ __forceinline__ int swz(int r, int k) {
    // XOR-swizzle word-column by row bits 3..5 to spread 8-row-strided
    // ds_read_b128 across banks (keeps 16B alignment).
    return k ^ (((r >> 3) & 7) << 2);
}

// ---- zero u, v -------------------------------------------------------------
__global__ void k_init_uv(float* buf) {
    int i = blockIdx.x * 1024 + threadIdx.x;
    if (i < 16384) buf[i] = 0.0f;
}

// ---- squared norms: one wave per row --------------------------------------
__global__ __launch_bounds__(64) void k_sqnorm(const float* __restrict__ XP,
                                               const float* __restrict__ XQ,
                                               float* __restrict__ xx,
                                               float* __restrict__ yy) {
    int row = blockIdx.x;
    int lane = threadIdx.x;
    const float* src = (row < NN) ? (XP + (size_t)row * DD)
                                  : (XQ + (size_t)(row - NN) * DD);
    float2 w = *(const float2*)&src[lane * 2];
    float sres = w.x * w.x + w.y * w.y;
    #pragma unroll
    for (int off = 32; off > 0; off >>= 1)
        sres += __shfl_down(sres, off, 64);
    if (lane == 0) {
        if (row < NN) xx[row] = sres;
        else          yy[row - NN] = sres;
    }
}

// ---- Mr = -20 * max(0, xx + yy - 2 XP.XQ^T) --------------------------------
// 128x128 block tile, full K=128 staged in LDS (128 KiB), 8x8 thread tile.
__global__ __launch_bounds__(256, 1) void k_gemm_mr(const float* __restrict__ XP,
                                                    const float* __restrict__ XQ,
                                                    const float* __restrict__ xx,
                                                    const float* __restrict__ yy,
                                                    float* __restrict__ Mr) {
    __shared__ float As[128][128];
    __shared__ float Bs[128][128];
    int rb = blockIdx.y * 128, cb = blockIdx.x * 128;
    int t = threadIdx.x;

    #pragma unroll
    for (int i = 0; i < 16; ++i) {
        int f = i * 256 + t;          // 0..4095 float4 slots
        int r = f >> 5;               // 32 float4 per row
        int k4 = (f & 31) * 4;
        *(float4*)&As[r][swz(r, k4)] = *(const float4*)&XP[(size_t)(rb + r) * DD + k4];
        *(float4*)&Bs[r][swz(r, k4)] = *(const float4*)&XQ[(size_t)(cb + r) * DD + k4];
    }
    __syncthreads();

    int ty = t >> 4, tx = t & 15;
    int r0 = ty * 8, c0 = tx * 8;
    float acc[8][8] = {};

    for (int k = 0; k < 128; k += 4) {
        float4 a[8], b[8];
        #pragma unroll
        for (int i = 0; i < 8; ++i) {
            a[i] = *(float4*)&As[r0 + i][swz(r0 + i, k)];
            b[i] = *(float4*)&Bs[c0 + i][swz(c0 + i, k)];
        }
        #pragma unroll
        for (int i = 0; i < 8; ++i)
            #pragma unroll
            for (int j = 0; j < 8; ++j)
                acc[i][j] += a[i].x * b[j].x + a[i].y * b[j].y +
                             a[i].z * b[j].z + a[i].w * b[j].w;
    }

    float yv[8];
    *(float4*)&yv[0] = *(const float4*)&yy[cb + c0];
    *(float4*)&yv[4] = *(const float4*)&yy[cb + c0 + 4];
    #pragma unroll
    for (int i = 0; i < 8; ++i) {
        int gr = rb + r0 + i;
        float xxi = xx[gr];
        float4 o0, o1;
        o0.x = NEG20 * fmaxf(xxi + yv[0] - 2.f * acc[i][0], 0.f);
        o0.y = NEG20 * fmaxf(xxi + yv[1] - 2.f * acc[i][1], 0.f);
        o0.z = NEG20 * fmaxf(xxi + yv[2] - 2.f * acc[i][2], 0.f);
        o0.w = NEG20 * fmaxf(xxi + yv[3] - 2.f * acc[i][3], 0.f);
        o1.x = NEG20 * fmaxf(xxi + yv[4] - 2.f * acc[i][4], 0.f);
        o1.y = NEG20 * fmaxf(xxi + yv[5] - 2.f * acc[i][5], 0.f);
        o1.z = NEG20 * fmaxf(xxi + yv[6] - 2.f * acc[i][6], 0.f);
        o1.w = NEG20 * fmaxf(xxi + yv[7] - 2.f * acc[i][7], 0.f);
        *(float4*)&Mr[(size_t)gr * MMX + cb + c0] = o0;
        *(float4*)&Mr[(size_t)gr * MMX + cb + c0 + 4] = o1;
    }
}

// ---- column-LSE partial: block = 1024 cols x 128 rows ----------------------
// part[chunk][m] = logsumexp over the chunk's rows of (Mr[n,m] + u[n])
__global__ __launch_bounds__(256) void k_colpass(const float* __restrict__ Mr,
                                                 const float* __restrict__ u,
                                                 float* __restrict__ part) {
    int c = blockIdx.x * 1024 + threadIdx.x * 4;
    int n0 = blockIdx.y * 128;
    float4 mx = make_float4(-1e30f, -1e30f, -1e30f, -1e30f);
    float4 s = make_float4(0.f, 0.f, 0.f, 0.f);
    #pragma unroll 4
    for (int r = 0; r < 128; ++r) {
        float un = u[n0 + r];
        float4 w = *(const float4*)&Mr[(size_t)(n0 + r) * MMX + c];
        w.x += un; w.y += un; w.z += un; w.w += un;
        lse_acc4(mx, s, w);
    }
    float4 o;
    o.x = mx.x + __logf(s.x);
    o.y = mx.y + __logf(s.y);
    o.z = mx.z + __logf(s.z);
    o.w = mx.w + __logf(s.w);
    *(float4*)&part[(size_t)blockIdx.y * MMX + c] = o;
}

// ---- combine 64 chunk-LSEs -> v[m] -----------------------------------------
__global__ __launch_bounds__(256) void k_colcombine(const float* __restrict__ part,
                                                    float* __restrict__ v) {
    int m = blockIdx.x * 256 + threadIdx.x;
    float mx = -1e30f, s = 0.f;
    #pragma unroll 8
    for (int ch = 0; ch < 64; ++ch)
        lse_acc(mx, s, part[(size_t)ch * MMX + m]);
    v[m] = LOGAB - (mx + __logf(s));
}

// ---- row-LSE: block = 4 rows, v reload amortized 4x ------------------------
__global__ __launch_bounds__(256) void k_rowpass(const float* __restrict__ Mr,
                                                 const float* __restrict__ v,
                                                 float* __restrict__ u) {
    int n0 = blockIdx.x * 4;
    int t = threadIdx.x;
    float4 mx[4], s[4];
    #pragma unroll
    for (int r = 0; r < 4; ++r) {
        mx[r] = make_float4(-1e30f, -1e30f, -1e30f, -1e30f);
        s[r] = make_float4(0.f, 0.f, 0.f, 0.f);
    }
    const float4* v4 = (const float4*)v;
    for (int i = t; i < MMX / 4; i += 256) {
        float4 vv = v4[i];
        #pragma unroll
        for (int r = 0; r < 4; ++r) {
            float4 w = *(const float4*)&Mr[(size_t)(n0 + r) * MMX + i * 4];
            w.x += vv.x; w.y += vv.y; w.z += vv.z; w.w += vv.w;
            lse_acc4(mx[r], s[r], w);
        }
    }
    __shared__ float sm[256], ss[256];
    #pragma unroll
    for (int r = 0; r < 4; ++r) {
        float m1 = mx[r].x, s1 = s[r].x;
        lse_merge(m1, s1, mx[r].y, s[r].y);
        lse_merge(m1, s1, mx[r].z, s[r].z);
        lse_merge(m1, s1, mx[r].w, s[r].w);
        sm[t] = m1; ss[t] = s1;
        __syncthreads();
        for (int off = 128; off > 0; off >>= 1) {
            if (t < off) {
                float ma = sm[t], sa = ss[t];
                lse_merge(ma, sa, sm[t + off], ss[t + off]);
                sm[t] = ma; ss[t] = sa;
            }
            __syncthreads();
        }
        if (t == 0) u[n0 + r] = LOGAB - (sm[0] + __logf(ss[0]));
        __syncthreads();
    }
}

// ---- pi = exp(Mr + u + v), in place ----------------------------------------
__global__ __launch_bounds__(256) void k_pi(float* __restrict__ Mr,
                                            const float* __restrict__ u,
                                            const float* __restrict__ v) {
    const float4* v4 = (const float4*)v;
    for (int i = blockIdx.x * 256 + threadIdx.x; i < NN * MMX / 4; i += 2048 * 256) {
        int n = i >> 11;        // 2048 float4 per row
        int m4 = i & 2047;
        float un = u[n];
        float4 vv = v4[m4];
        float4* p = (float4*)Mr + i;
        float4 w = *p;
        w.x = __expf(w.x + un + vv.x);
        w.y = __expf(w.y + un + vv.y);
        w.z = __expf(w.z + un + vv.z);
        w.w = __expf(w.w + un + vv.w);
        *p = w;
    }
}

// ---- mapped = 8192 * pi @ XQ  (block = 32 rows, thread = 4r x 4d) ----------
__global__ __launch_bounds__(256) void k_mapped(const float* __restrict__ pi,
                                                const float* __restrict__ XQ,
                                                float* __restrict__ mapped) {
    __shared__ float XQs[64][128];
    __shared__ float PIs[32][64];
    int r0 = blockIdx.x * 32;
    int t = threadIdx.x;
    int dg = (t & 31) * 4;
    int rg = (t >> 5) * 4;
    float4 acc[4];
    #pragma unroll
    for (int j = 0; j < 4; ++j) acc[j] = make_float4(0.f, 0.f, 0.f, 0.f);

    for (int mb = 0; mb < MMX; mb += 64) {
        __syncthreads();
        #pragma unroll
        for (int i = 0; i < 8; ++i) {
            int f = i * 256 + t;
            int rr = f >> 5;
            int k4 = (f & 31) * 4;
            *(float4*)&XQs[rr][k4] = *(const float4*)&XQ[(size_t)(mb + rr) * DD + k4];
        }
        #pragma unroll
        for (int i = 0; i < 2; ++i) {
            int f = i * 256 + t;
            int rr = f >> 4;
            int c4 = (f & 15) * 4;
            *(float4*)&PIs[rr][c4] = *(const float4*)&pi[(size_t)(r0 + rr) * MMX + mb + c4];
        }
        __syncthreads();
        for (int mm = 0; mm < 64; mm += 4) {
            float4 q0 = *(float4*)&XQs[mm + 0][dg];
            float4 q1 = *(float4*)&XQs[mm + 1][dg];
            float4 q2 = *(float4*)&XQs[mm + 2][dg];
            float4 q3 = *(float4*)&XQs[mm + 3][dg];
            #pragma unroll
            for (int j = 0; j < 4; ++j) {
                float4 p = *(float4*)&PIs[rg + j][mm];
                acc[j].x += p.x * q0.x + p.y * q1.x + p.z * q2.x + p.w * q3.x;
                acc[j].y += p.x * q0.y + p.y * q1.y + p.z * q2.y + p.w * q3.y;
                acc[j].z += p.x * q0.z + p.y * q1.z + p.z * q2.z + p.w * q3.z;
                acc[j].w += p.x * q0.w + p.y * q1.w + p.z * q2.w + p.w * q3.w;
            }
        }
    }
    #pragma unroll
    for (int j = 0; j < 4; ++j) {
        float4 o = acc[j];
        o.x *= 8192.f; o.y *= 8192.f; o.z *= 8192.f; o.w *= 8192.f;
        *(float4*)&mapped[(size_t)(r0 + rg + j) * DD + dg] = o;
    }
}

extern "C" void kernel_launch(void* const* d_in, const int* in_sizes, int n_in,
                              void* d_out, int out_size, void* d_ws, size_t ws_size,
                              hipStream_t stream) {
    const float* XP = (const float*)d_in[0];
    const float* XQ = (const float*)d_in[1];
    float* out = (float*)d_out;
    float* Mr = out + (size_t)NN * DD;   // pi region holds Mr, later pi
    float* u = out;                      // scratch inside mapped region
    float* v = out + 8192;
    float* xx = out + 40960;
    float* yy = out + 49152;
    float* part = out + 65536;           // 64 x 8192 chunk partials (2 MiB)

    k_init_uv<<<16, 1024, 0, stream>>>(out);
    k_sqnorm<<<NN + MMX, 64, 0, stream>>>(XP, XQ, xx, yy);
    k_gemm_mr<<<dim3(64, 64), 256, 0, stream>>>(XP, XQ, xx, yy, Mr);

    for (int it = 0; it < NITER; ++it) {
        k_colpass<<<dim3(8, 64), 256, 0, stream>>>(Mr, u, part);
        k_colcombine<<<32, 256, 0, stream>>>(part, v);
        k_rowpass<<<2048, 256, 0, stream>>>(Mr, v, u);
    }

    k_pi<<<2048, 256, 0, stream>>>(Mr, u, v);
    k_mapped<<<256, 256, 0, stream>>>(Mr, XQ, out);
}